// Round 5
// baseline (1728.583 us; speedup 1.0000x reference)
//
#include <hip/hip_runtime.h>
#include <math.h>

#define LTOK 2080
#define DIM 128
#define NH 4
#define W0C 52
#define HFI 160
#define WFI 208
#define NPIX (HFI*WFI)   // 33280
#define CFCH 32
#define NSPLIT 5
#define PARTSTRIDE 1056  // 32*32 acc + 32 l

// ---------------- transpose (C,L) -> (L,C) ----------------
__global__ __launch_bounds__(256) void transpose_kernel(const float* __restrict__ in,
                                                        float* __restrict__ out)
{
    __shared__ float T[32][33];
    int l0 = blockIdx.x * 32, c0 = blockIdx.y * 32;
    int t = threadIdx.x;
    #pragma unroll
    for (int e = 0; e < 4; ++e) {
        int idx = t + e * 256; int i = idx >> 5, j = idx & 31;
        T[i][j] = in[(size_t)(c0 + i) * LTOK + l0 + j];
    }
    __syncthreads();
    #pragma unroll
    for (int e = 0; e < 4; ++e) {
        int idx = t + e * 256; int j2 = idx >> 5, i2 = idx & 31;
        out[(size_t)(l0 + j2) * DIM + c0 + i2] = T[i2][j2];
    }
}

// ---------------- generic GEMM: C = alpha * A(MxK) * B(NxK)^T + bias ----------------
__global__ __launch_bounds__(256) void gemm_nt_kernel(const float* __restrict__ A, int lda,
                                                      const float* __restrict__ B, int ldb,
                                                      float* __restrict__ C, int ldc,
                                                      int K, float alpha,
                                                      const float* __restrict__ bias, int relu)
{
    __shared__ float As[32][33];
    __shared__ float Bs[32][33];
    int tid = threadIdx.x;
    int n0 = blockIdx.x * 32, m0 = blockIdx.y * 32;
    int c = tid & 31, r8 = tid >> 5;
    float acc[4] = {0.f, 0.f, 0.f, 0.f};
    for (int k0 = 0; k0 < K; k0 += 32) {
        #pragma unroll
        for (int e = 0; e < 4; ++e) {
            int l = tid + e * 256;
            int i = l >> 5, k = l & 31;
            As[k][i] = A[(size_t)(m0 + i) * lda + k0 + k];
            Bs[k][i] = B[(size_t)(n0 + i) * ldb + k0 + k];
        }
        __syncthreads();
        #pragma unroll
        for (int k = 0; k < 32; ++k) {
            float bv = Bs[k][c];
            #pragma unroll
            for (int jj = 0; jj < 4; ++jj)
                acc[jj] += As[k][4 * r8 + jj] * bv;
        }
        __syncthreads();
    }
    #pragma unroll
    for (int jj = 0; jj < 4; ++jj) {
        float v = alpha * acc[jj];
        if (bias) v += bias[n0 + c];
        if (relu) v = fmaxf(v, 0.f);
        C[(size_t)(m0 + 4 * r8 + jj) * ldc + n0 + c] = v;
    }
}

// ---------------- score GEMM + fused softmax-stat partials ----------------
__global__ __launch_bounds__(256) void gemm_score_kernel(const float* __restrict__ A,
                                                         const float* __restrict__ B,
                                                         float* __restrict__ C,
                                                         float2* __restrict__ prs,
                                                         float2* __restrict__ pcs)
{
    __shared__ float As[32][33];
    __shared__ float Bs[32][33];
    __shared__ float cmS[8][32];
    __shared__ float ceS[8][32];
    int tid = threadIdx.x;
    int n0 = blockIdx.x * 32, m0 = blockIdx.y * 32;
    int c = tid & 31, r8 = tid >> 5;
    float acc[4] = {0.f, 0.f, 0.f, 0.f};
    for (int k0 = 0; k0 < 128; k0 += 32) {
        #pragma unroll
        for (int e = 0; e < 4; ++e) {
            int l = tid + e * 256;
            int i = l >> 5, k = l & 31;
            As[k][i] = A[(size_t)(m0 + i) * 128 + k0 + k];
            Bs[k][i] = B[(size_t)(n0 + i) * 128 + k0 + k];
        }
        __syncthreads();
        #pragma unroll
        for (int k = 0; k < 32; ++k) {
            float bv = Bs[k][c];
            #pragma unroll
            for (int jj = 0; jj < 4; ++jj)
                acc[jj] += As[k][4 * r8 + jj] * bv;
        }
        __syncthreads();
    }
    float v[4];
    #pragma unroll
    for (int jj = 0; jj < 4; ++jj) {
        v[jj] = 10.f * acc[jj];
        C[(size_t)(m0 + 4 * r8 + jj) * LTOK + n0 + c] = v[jj];
    }
    #pragma unroll
    for (int jj = 0; jj < 4; ++jj) {
        float m = v[jj];
        #pragma unroll
        for (int mm = 16; mm >= 1; mm >>= 1) m = fmaxf(m, __shfl_xor(m, mm, 32));
        float e = __expf(v[jj] - m);
        #pragma unroll
        for (int mm = 16; mm >= 1; mm >>= 1) e += __shfl_xor(e, mm, 32);
        if (c == 0) prs[(size_t)blockIdx.x * LTOK + m0 + 4 * r8 + jj] = make_float2(m, e);
    }
    float cmx = fmaxf(fmaxf(v[0], v[1]), fmaxf(v[2], v[3]));
    float cex = __expf(v[0] - cmx) + __expf(v[1] - cmx) + __expf(v[2] - cmx) + __expf(v[3] - cmx);
    cmS[r8][c] = cmx; ceS[r8][c] = cex;
    __syncthreads();
    if (r8 == 0) {
        float M = cmS[0][c], S = ceS[0][c];
        #pragma unroll
        for (int k = 1; k < 8; ++k) {
            float m2 = cmS[k][c], s2 = ceS[k][c];
            if (m2 > M) { S = S * __expf(M - m2) + s2; M = m2; }
            else        { S += s2 * __expf(m2 - M); }
        }
        pcs[(size_t)blockIdx.y * LTOK + n0 + c] = make_float2(M, S);
    }
}

// ---------------- merge 65 stat partials per row/col; store max + 1/sum ----------------
__global__ __launch_bounds__(256) void stats_combine_kernel(const float2* __restrict__ prs,
                                                            const float2* __restrict__ pcs,
                                                            float* __restrict__ rowmax,
                                                            float* __restrict__ rsinv,
                                                            float* __restrict__ colmax,
                                                            float* __restrict__ csinv)
{
    int id = blockIdx.x * 256 + threadIdx.x;
    if (id >= 2 * LTOK) return;
    const float2* p = (id < LTOK) ? (prs + id) : (pcs + (id - LTOK));
    float M = -1e30f;
    for (int i = 0; i < 65; ++i) M = fmaxf(M, p[(size_t)i * LTOK].x);
    float S = 0.f;
    for (int i = 0; i < 65; ++i) {
        float2 f = p[(size_t)i * LTOK];
        S += f.y * __expf(f.x - M);
    }
    if (id < LTOK) { rowmax[id] = M; rsinv[id] = 1.f / S; }
    else           { colmax[id - LTOK] = M; csinv[id - LTOK] = 1.f / S; }
}

// ---------------- P = exp(2S-rm-cm)*rsinv*csinv (in place) + argmax partials ----------------
__global__ __launch_bounds__(256) void dualp_argmax_kernel(float* __restrict__ S,
                                                           const float* __restrict__ rm,
                                                           const float* __restrict__ rsinv,
                                                           const float* __restrict__ cm,
                                                           const float* __restrict__ csinv,
                                                           float* __restrict__ prv,
                                                           int* __restrict__ pri,
                                                           float* __restrict__ pcv,
                                                           int* __restrict__ pci)
{
    __shared__ float cvS[8][32];
    __shared__ int   ciS[8][32];
    int tid = threadIdx.x;
    int n0 = blockIdx.x * 32, m0 = blockIdx.y * 32;
    int c = tid & 31, r8 = tid >> 5;
    int col = n0 + c;
    float cmv = cm[col], csv = csinv[col];
    float p[4];
    #pragma unroll
    for (int jj = 0; jj < 4; ++jj) {
        int row = m0 + 4 * r8 + jj;
        size_t o = (size_t)row * LTOK + col;
        float s = S[o];
        float pv = __expf(2.f * s - rm[row] - cmv) * (rsinv[row] * csv);
        S[o] = pv;
        p[jj] = pv;
    }
    #pragma unroll
    for (int jj = 0; jj < 4; ++jj) {
        float bv = p[jj]; int bi = col;
        #pragma unroll
        for (int mm = 16; mm >= 1; mm >>= 1) {
            float ov = __shfl_xor(bv, mm, 32);
            int   oi = __shfl_xor(bi, mm, 32);
            if (ov > bv || (ov == bv && oi < bi)) { bv = ov; bi = oi; }
        }
        if (c == 0) {
            prv[(size_t)blockIdx.x * LTOK + m0 + 4 * r8 + jj] = bv;
            pri[(size_t)blockIdx.x * LTOK + m0 + 4 * r8 + jj] = bi;
        }
    }
    float bv = p[0]; int bi = m0 + 4 * r8;
    #pragma unroll
    for (int jj = 1; jj < 4; ++jj)
        if (p[jj] > bv) { bv = p[jj]; bi = m0 + 4 * r8 + jj; }
    cvS[r8][c] = bv; ciS[r8][c] = bi;
    __syncthreads();
    if (r8 == 0) {
        #pragma unroll
        for (int k = 1; k < 8; ++k)
            if (cvS[k][c] > bv) { bv = cvS[k][c]; bi = ciS[k][c]; }
        pcv[(size_t)blockIdx.y * LTOK + col] = bv;
        pci[(size_t)blockIdx.y * LTOK + col] = bi;
    }
}

// ---------------- merge 65 argmax partials ----------------
__global__ __launch_bounds__(256) void argmax_combine_kernel(const float* __restrict__ prv,
                                                             const int* __restrict__ pri,
                                                             const float* __restrict__ pcv,
                                                             const int* __restrict__ pci,
                                                             int* __restrict__ idx0,
                                                             float* __restrict__ conf,
                                                             int* __restrict__ idx1)
{
    int id = blockIdx.x * 256 + threadIdx.x;
    if (id >= 2 * LTOK) return;
    if (id < LTOK) {
        float best = -1e30f; int bi = 0;
        for (int i = 0; i < 65; ++i) {
            float v = prv[(size_t)i * LTOK + id];
            if (v > best) { best = v; bi = pri[(size_t)i * LTOK + id]; }
        }
        idx0[id] = bi; conf[id] = best;
    } else {
        int colI = id - LTOK;
        float best = -1e30f; int bi = 0;
        for (int i = 0; i < 65; ++i) {
            float v = pcv[(size_t)i * LTOK + colI];
            if (v > best) { best = v; bi = pci[(size_t)i * LTOK + colI]; }
        }
        idx1[colI] = bi;
    }
}

// ---------------- MHA partial (flash, KV-split, shfl-PV, fp32) ----------------
// P stays in registers after the score phase; PV uses __shfl broadcasts within
// each 32-lane half-wave (which owns 4 q-rows x 32 cols of P) instead of an
// LDS round-trip. LDS ops/tile drop ~2x; one barrier per tile removed.
__global__ __launch_bounds__(256, 5) void mha_partial_kernel(const float* __restrict__ qsrc,
                                                             const float* __restrict__ kvsrc,
                                                             float* __restrict__ part)
{
    __shared__ float Qs[32][36];
    __shared__ float Ks[64][36];
    __shared__ float Vt[32][68];
    int tid = threadIdx.x;
    int qb = blockIdx.x, h = blockIdx.y, ns = blockIdx.z;
    int c = tid & 31, r8 = tid >> 5;
    int row0 = 4 * r8;
    const float sc = 0.17677669529663687f; // 1/sqrt(32)

    {
        int r = tid >> 3, d4 = (tid & 7) << 2;
        float4 q = *(const float4*)(qsrc + (size_t)(qb * 32 + r) * 384 + h * 32 + d4);
        *(float4*)(&Qs[r][d4]) = q;
    }
    float acc[4] = {0.f, 0.f, 0.f, 0.f};
    float lacc[4] = {0.f, 0.f, 0.f, 0.f};
    __syncthreads();

    const int koff = 128 + h * 32, voff = 256 + h * 32;
    for (int t = ns; t < 33; t += NSPLIT) {
        int j0 = t * 64;
        // ---- stage K (64x32) and V transposed (32x64) ----
        {
            int r = tid >> 3, d4 = (tid & 7) << 2;
            int j1 = j0 + r, j2 = j0 + r + 32;
            float4 k1 = *(const float4*)(kvsrc + (size_t)j1 * 384 + koff + d4);
            float4 v1 = *(const float4*)(kvsrc + (size_t)j1 * 384 + voff + d4);
            float4 k2 = make_float4(0.f, 0.f, 0.f, 0.f);
            float4 v2 = make_float4(0.f, 0.f, 0.f, 0.f);
            if (j2 < LTOK) {
                k2 = *(const float4*)(kvsrc + (size_t)j2 * 384 + koff + d4);
                v2 = *(const float4*)(kvsrc + (size_t)j2 * 384 + voff + d4);
            }
            *(float4*)(&Ks[r][d4])      = k1;
            *(float4*)(&Ks[r + 32][d4]) = k2;
            Vt[d4 + 0][r] = v1.x; Vt[d4 + 1][r] = v1.y; Vt[d4 + 2][r] = v1.z; Vt[d4 + 3][r] = v1.w;
            Vt[d4 + 0][r + 32] = v2.x; Vt[d4 + 1][r + 32] = v2.y; Vt[d4 + 2][r + 32] = v2.z; Vt[d4 + 3][r + 32] = v2.w;
        }
        __syncthreads();
        // ---- scores for cols c and c+32 across 4 rows ----
        float s1[4] = {0.f, 0.f, 0.f, 0.f};
        float s2[4] = {0.f, 0.f, 0.f, 0.f};
        #pragma unroll
        for (int d4 = 0; d4 < 8; ++d4) {
            float4 ka = *(const float4*)(&Ks[c][d4 << 2]);
            float4 kb = *(const float4*)(&Ks[c + 32][d4 << 2]);
            #pragma unroll
            for (int jj = 0; jj < 4; ++jj) {
                float4 q = *(const float4*)(&Qs[row0 + jj][d4 << 2]);
                s1[jj] += q.x * ka.x + q.y * ka.y + q.z * ka.z + q.w * ka.w;
                s2[jj] += q.x * kb.x + q.y * kb.y + q.z * kb.z + q.w * kb.w;
            }
        }
        bool ok2 = (j0 + 32 + c) < LTOK;
        float p1[4], p2[4];
        #pragma unroll
        for (int jj = 0; jj < 4; ++jj) {
            p1[jj] = __expf(s1[jj] * sc);
            p2[jj] = ok2 ? __expf(s2[jj] * sc) : 0.f;
            lacc[jj] += p1[jj] + p2[jj];
        }
        // ---- PV via shfl: lane j of this half-wave holds P[row][j0+j] (p1) and
        //      P[row][j0+32+j] (p2). acc[jj] += sum_j P[row0+jj][j] * Vt[c][j]. ----
        #pragma unroll
        for (int j4 = 0; j4 < 16; ++j4) {
            float4 vv = *(const float4*)(&Vt[c][j4 << 2]);
            int jb = j4 << 2;
            #pragma unroll
            for (int k = 0; k < 4; ++k) {
                int j = jb + k;
                float vk = (k == 0) ? vv.x : (k == 1) ? vv.y : (k == 2) ? vv.z : vv.w;
                if (j < 32) {
                    #pragma unroll
                    for (int jj = 0; jj < 4; ++jj)
                        acc[jj] += __shfl(p1[jj], j, 32) * vk;
                } else {
                    #pragma unroll
                    for (int jj = 0; jj < 4; ++jj)
                        acc[jj] += __shfl(p2[jj], j - 32, 32) * vk;
                }
            }
        }
        __syncthreads();
    }
    float* pb = part + (size_t)((qb * NH + h) * NSPLIT + ns) * PARTSTRIDE;
    #pragma unroll
    for (int jj = 0; jj < 4; ++jj)
        pb[(row0 + jj) * 32 + c] = acc[jj];
    #pragma unroll
    for (int jj = 0; jj < 4; ++jj) {
        float l = lacc[jj];
        #pragma unroll
        for (int mm = 16; mm >= 1; mm >>= 1) l += __shfl_xor(l, mm, 32);
        if (c == 0) pb[1024 + row0 + jj] = l;
    }
}

// ---------------- MHA combine ----------------
__global__ __launch_bounds__(256) void mha_combine_kernel(const float* __restrict__ part,
                                                          float* __restrict__ out)
{
    int tid = threadIdx.x;
    int qb = blockIdx.x, h = blockIdx.y;
    int c = tid & 31, r8 = tid >> 5;
    int row0 = 4 * r8;
    const float* pb = part + (size_t)(qb * NH + h) * NSPLIT * PARTSTRIDE;
    #pragma unroll
    for (int jj = 0; jj < 4; ++jj) {
        int row = row0 + jj;
        float num = 0.f, den = 0.f;
        #pragma unroll
        for (int ns = 0; ns < NSPLIT; ++ns) {
            num += pb[ns * PARTSTRIDE + row * 32 + c];
            den += pb[ns * PARTSTRIDE + 1024 + row];
        }
        out[(size_t)(qb * 32 + row) * DIM + h * 32 + c] = num / den;
    }
}

// ---------------- residual add + LayerNorm (in place on f) ----------------
__global__ __launch_bounds__(256) void addln_kernel(float* __restrict__ f,
                                                    const float* __restrict__ t,
                                                    const float* __restrict__ g,
                                                    const float* __restrict__ b)
{
    int row = blockIdx.x * 4 + (threadIdx.x >> 6);
    int lane = threadIdx.x & 63;
    size_t base = (size_t)row * DIM;
    float x0 = f[base + lane] + t[base + lane];
    float x1 = f[base + lane + 64] + t[base + lane + 64];
    float s = x0 + x1;
    #pragma unroll
    for (int mm = 32; mm >= 1; mm >>= 1) s += __shfl_xor(s, mm, 64);
    float mean = s * (1.f / 128.f);
    float d0 = x0 - mean, d1 = x1 - mean;
    float v = d0 * d0 + d1 * d1;
    #pragma unroll
    for (int mm = 32; mm >= 1; mm >>= 1) v += __shfl_xor(v, mm, 64);
    float rstd = rsqrtf(v * (1.f / 128.f) + 1e-5f);
    f[base + lane]      = d0 * rstd * g[lane] + b[lane];
    f[base + lane + 64] = d1 * rstd * g[lane + 64] + b[lane + 64];
}

// ---------------- L2-normalize rows ----------------
__global__ __launch_bounds__(256) void normrows_kernel(const float* __restrict__ f,
                                                       float* __restrict__ o)
{
    int row = blockIdx.x * 4 + (threadIdx.x >> 6);
    int lane = threadIdx.x & 63;
    size_t base = (size_t)row * DIM;
    float x0 = f[base + lane], x1 = f[base + lane + 64];
    float v = x0 * x0 + x1 * x1;
    #pragma unroll
    for (int mm = 32; mm >= 1; mm >>= 1) v += __shfl_xor(v, mm, 64);
    float inv = 1.f / fmaxf(sqrtf(v), 1e-12f);
    o[base + lane] = x0 * inv;
    o[base + lane + 64] = x1 * inv;
}

// ---------------- match outputs: valid, conf, pt0 ----------------
__global__ __launch_bounds__(256) void match_kernel(const int* __restrict__ idx0,
                                                    const int* __restrict__ idx1,
                                                    const float* __restrict__ conf,
                                                    float* __restrict__ out_valid,
                                                    float* __restrict__ out_conf,
                                                    float* __restrict__ out_pt0)
{
    int i = blockIdx.x * 256 + threadIdx.x;
    if (i >= LTOK) return;
    int j = idx0[i];
    bool valid = (idx1[j] == i) && (conf[i] > 0.2f);
    out_valid[i] = valid ? 1.f : 0.f;
    out_conf[i] = conf[i];
    out_pt0[2 * i]     = (float)(i % W0C) * 8.f + 4.f;
    out_pt0[2 * i + 1] = (float)(i / W0C) * 8.f + 4.f;
}

// ---------------- fine projection ----------------
__global__ __launch_bounds__(256) void fine_proj_kernel(const float* __restrict__ fin,
                                                        const float* __restrict__ w,
                                                        const float* __restrict__ b,
                                                        float* __restrict__ fout)
{
    __shared__ float ws_[32][32];
    __shared__ float bs[32];
    int t = threadIdx.x;
    #pragma unroll
    for (int e = 0; e < 4; ++e) { int l = t + e * 256; ws_[l >> 5][l & 31] = w[l]; }
    if (t < 32) bs[t] = b[t];
    __syncthreads();
    int p = blockIdx.x * 256 + t;
    if (p >= NPIX) return;
    float x[32];
    #pragma unroll
    for (int cc = 0; cc < 32; ++cc) x[cc] = fin[(size_t)cc * NPIX + p];
    #pragma unroll
    for (int o = 0; o < 32; ++o) {
        float a = bs[o];
        #pragma unroll
        for (int cc = 0; cc < 32; ++cc) a += ws_[o][cc] * x[cc];
        fout[(size_t)o * NPIX + p] = a;
    }
}

// ---------------- fine match ----------------
__global__ __launch_bounds__(64) void fine_match_kernel(const int* __restrict__ idx0,
                                                        const float* __restrict__ f0p,
                                                        const float* __restrict__ f1p,
                                                        float* __restrict__ out_pt1)
{
    int i = blockIdx.x;
    int l = threadIdx.x;
    int j = idx0[i];
    int m0x = i % W0C, m0y = i / W0C;
    int m1x = j % W0C, m1y = j / W0C;
    int c0x = m0x * 4, c0y = m0y * 4, c1x = m1x * 4, c1y = m1y * 4;
    bool inb = (c0x - 2 >= 0) && (c0x + 2 < WFI) && (c0y - 2 >= 0) && (c0y + 2 < HFI)
            && (c1x - 2 >= 0) && (c1x + 2 < WFI) && (c1y - 2 >= 0) && (c1y + 2 < HFI);
    int cy0 = min(max(c0y, 2), HFI - 3), cx0 = min(max(c0x, 2), WFI - 3);
    int cy1 = min(max(c1y, 2), HFI - 3), cx1 = min(max(c1x, 2), WFI - 3);
    int dy = l / 5 - 2, dx = l % 5 - 2;
    float corr = -1e30f;
    if (l < 25) {
        float a = 0.f;
        int p0 = cy0 * WFI + cx0;
        int p1 = (cy1 + dy) * WFI + (cx1 + dx);
        #pragma unroll
        for (int cc = 0; cc < 32; ++cc)
            a += f0p[(size_t)cc * NPIX + p0] * f1p[(size_t)cc * NPIX + p1];
        corr = a;
    }
    float mx = corr;
    #pragma unroll
    for (int mm = 32; mm >= 1; mm >>= 1) mx = fmaxf(mx, __shfl_xor(mx, mm, 64));
    float p = (l < 25) ? expf(corr - mx) : 0.f;
    float s = p, sx = p * (float)dx, sy = p * (float)dy;
    #pragma unroll
    for (int mm = 32; mm >= 1; mm >>= 1) {
        s  += __shfl_xor(s, mm, 64);
        sx += __shfl_xor(sx, mm, 64);
        sy += __shfl_xor(sy, mm, 64);
    }
    if (l == 0) {
        float offx = sx / s, offy = sy / s;
        float px = (float)m1x * 8.f + 4.f;
        float py = (float)m1y * 8.f + 4.f;
        if (inb) { px += offx * 2.f; py += offy * 2.f; }
        out_pt1[2 * i]     = px;
        out_pt1[2 * i + 1] = py;
    }
}

// ---------------- host launch ----------------
extern "C" void kernel_launch(void* const* d_in, const int* in_sizes, int n_in,
                              void* d_out, int out_size, void* d_ws, size_t ws_size,
                              hipStream_t stream) {
    (void)in_sizes; (void)n_in; (void)out_size; (void)ws_size;
    const float* coarse0 = (const float*)d_in[0];
    const float* coarse1 = (const float*)d_in[1];
    const float* fine0   = (const float*)d_in[2];
    const float* fine1   = (const float*)d_in[3];
    const float* sa_in_w  = (const float*)d_in[4];
    const float* sa_in_b  = (const float*)d_in[5];
    const float* sa_out_w = (const float*)d_in[6];
    const float* sa_out_b = (const float*)d_in[7];
    const float* ca_in_w  = (const float*)d_in[8];
    const float* ca_in_b  = (const float*)d_in[9];
    const float* ca_out_w = (const float*)d_in[10];
    const float* ca_out_b = (const float*)d_in[11];
    const float* sn_g = (const float*)d_in[12];
    const float* sn_b = (const float*)d_in[13];
    const float* cn_g = (const float*)d_in[14];
    const float* cn_b = (const float*)d_in[15];
    const float* ffn_w1 = (const float*)d_in[16];
    const float* ffn_b1 = (const float*)d_in[17];
    const float* ffn_w2 = (const float*)d_in[18];
    const float* ffn_b2 = (const float*)d_in[19];
    const float* fn_g = (const float*)d_in[20];
    const float* fn_b = (const float*)d_in[21];
    const float* proj_w = (const float*)d_in[22];
    const float* proj_b = (const float*)d_in[23];

    float* w = (float*)d_ws;
    float* f0   = w; w += (size_t)LTOK * DIM;
    float* f1   = w; w += (size_t)LTOK * DIM;
    float* qkv0 = w; w += (size_t)LTOK * 384;
    float* qkv1 = w; w += (size_t)LTOK * 384;
    float* att  = w; w += (size_t)LTOK * DIM;
    float* tmp0 = w; w += (size_t)LTOK * DIM;
    float* tmp1 = w; w += (size_t)LTOK * DIM;
    float* hid  = w; w += (size_t)LTOK * 256;
    float* f0n  = w; w += (size_t)LTOK * DIM;
    float* f1n  = w; w += (size_t)LTOK * DIM;
    float* f0p  = w; w += (size_t)CFCH * NPIX;
    float* f1p  = w; w += (size_t)CFCH * NPIX;
    float* part = w; w += (size_t)65 * NH * NSPLIT * PARTSTRIDE;
    float* rowmax = w; w += LTOK;
    float* rsinv  = w; w += LTOK;
    float* colmax = w; w += LTOK;
    float* csinv  = w; w += LTOK;
    float* conf   = w; w += LTOK;
    int* idx0 = (int*)w; w += LTOK;
    int* idx1 = (int*)w; w += LTOK;

    // matching-tail partials alias the (dead after transformer loop) qkv buffers
    float2* prs = (float2*)qkv0;
    float2* pcs = (float2*)(qkv0 + 2 * 65 * LTOK);
    float*  prv = qkv1;
    int*    pri = (int*)(qkv1 + 65 * LTOK);
    float*  pcv = qkv1 + 2 * 65 * LTOK;
    int*    pci = (int*)(qkv1 + 3 * 65 * LTOK);

    float* Pout = (float*)d_out;
    float* out_valid = Pout + (size_t)LTOK * LTOK;
    float* out_conf  = out_valid + LTOK;
    float* out_pt0   = out_conf + LTOK;
    float* out_pt1   = out_pt0 + 2 * LTOK;

    dim3 b256(256);
    dim3 gT(65, 4);
    dim3 gMHA(65, 4, NSPLIT);
    dim3 gCMB(65, 4);
    transpose_kernel<<<gT, b256, 0, stream>>>(coarse0, f0);
    transpose_kernel<<<gT, b256, 0, stream>>>(coarse1, f1);

    for (int i = 0; i < 2; ++i) {
        const float* saw = sa_in_w + (size_t)i * 384 * 128;
        const float* sab = sa_in_b + (size_t)i * 384;
        const float* sow = sa_out_w + (size_t)i * 128 * 128;
        const float* sob = sa_out_b + (size_t)i * 128;
        const float* caw = ca_in_w + (size_t)i * 384 * 128;
        const float* cab = ca_in_b + (size_t)i * 384;
        const float* cow = ca_out_w + (size_t)i * 128 * 128;
        const float* cob = ca_out_b + (size_t)i * 128;
        const float* w1 = ffn_w1 + (size_t)i * 256 * 128;
        const float* b1 = ffn_b1 + (size_t)i * 256;
        const float* w2 = ffn_w2 + (size_t)i * 128 * 256;
        const float* b2 = ffn_b2 + (size_t)i * 128;

        // ---- self attention ----
        gemm_nt_kernel<<<dim3(12, 65), b256, 0, stream>>>(f0, 128, saw, 128, qkv0, 384, 128, 1.f, sab, 0);
        gemm_nt_kernel<<<dim3(12, 65), b256, 0, stream>>>(f1, 128, saw, 128, qkv1, 384, 128, 1.f, sab, 0);
        mha_partial_kernel<<<gMHA, b256, 0, stream>>>(qkv0, qkv0, part);
        mha_combine_kernel<<<gCMB, b256, 0, stream>>>(part, att);
        gemm_nt_kernel<<<dim3(4, 65), b256, 0, stream>>>(att, 128, sow, 128, tmp0, 128, 128, 1.f, sob, 0);
        mha_partial_kernel<<<gMHA, b256, 0, stream>>>(qkv1, qkv1, part);
        mha_combine_kernel<<<gCMB, b256, 0, stream>>>(part, att);
        gemm_nt_kernel<<<dim3(4, 65), b256, 0, stream>>>(att, 128, sow, 128, tmp1, 128, 128, 1.f, sob, 0);
        addln_kernel<<<520, b256, 0, stream>>>(f0, tmp0, sn_g + (size_t)i * 128, sn_b + (size_t)i * 128);
        addln_kernel<<<520, b256, 0, stream>>>(f1, tmp1, sn_g + (size_t)i * 128, sn_b + (size_t)i * 128);

        // ---- cross attention ----
        gemm_nt_kernel<<<dim3(12, 65), b256, 0, stream>>>(f0, 128, caw, 128, qkv0, 384, 128, 1.f, cab, 0);
        gemm_nt_kernel<<<dim3(12, 65), b256, 0, stream>>>(f1, 128, caw, 128, qkv1, 384, 128, 1.f, cab, 0);
        mha_partial_kernel<<<gMHA, b256, 0, stream>>>(qkv0, qkv1, part);
        mha_combine_kernel<<<gCMB, b256, 0, stream>>>(part, att);
        gemm_nt_kernel<<<dim3(4, 65), b256, 0, stream>>>(att, 128, cow, 128, tmp0, 128, 128, 1.f, cob, 0);
        mha_partial_kernel<<<gMHA, b256, 0, stream>>>(qkv1, qkv0, part);
        mha_combine_kernel<<<gCMB, b256, 0, stream>>>(part, att);
        gemm_nt_kernel<<<dim3(4, 65), b256, 0, stream>>>(att, 128, cow, 128, tmp1, 128, 128, 1.f, cob, 0);
        addln_kernel<<<520, b256, 0, stream>>>(f0, tmp0, cn_g + (size_t)i * 128, cn_b + (size_t)i * 128);
        addln_kernel<<<520, b256, 0, stream>>>(f1, tmp1, cn_g + (size_t)i * 128, cn_b + (size_t)i * 128);

        // ---- FFN ----
        gemm_nt_kernel<<<dim3(8, 65), b256, 0, stream>>>(f0, 128, w1, 128, hid, 256, 128, 1.f, b1, 1);
        gemm_nt_kernel<<<dim3(4, 65), b256, 0, stream>>>(hid, 256, w2, 256, tmp0, 128, 256, 1.f, b2, 0);
        addln_kernel<<<520, b256, 0, stream>>>(f0, tmp0, fn_g + (size_t)i * 128, fn_b + (size_t)i * 128);
        gemm_nt_kernel<<<dim3(8, 65), b256, 0, stream>>>(f1, 128, w1, 128, hid, 256, 128, 1.f, b1, 1);
        gemm_nt_kernel<<<dim3(4, 65), b256, 0, stream>>>(hid, 256, w2, 256, tmp1, 128, 256, 1.f, b2, 0);
        addln_kernel<<<520, b256, 0, stream>>>(f1, tmp1, fn_g + (size_t)i * 128, fn_b + (size_t)i * 128);
    }

    // ---- matching (2 matrix passes total) ----
    normrows_kernel<<<520, b256, 0, stream>>>(f0, f0n);
    normrows_kernel<<<520, b256, 0, stream>>>(f1, f1n);
    gemm_score_kernel<<<dim3(65, 65), b256, 0, stream>>>(f0n, f1n, Pout, prs, pcs);
    stats_combine_kernel<<<17, b256, 0, stream>>>(prs, pcs, rowmax, rsinv, colmax, csinv);
    dualp_argmax_kernel<<<dim3(65, 65), b256, 0, stream>>>(Pout, rowmax, rsinv, colmax, csinv,
                                                           prv, pri, pcv, pci);
    argmax_combine_kernel<<<17, b256, 0, stream>>>(prv, pri, pcv, pci, idx0, conf, idx1);
    match_kernel<<<9, b256, 0, stream>>>(idx0, idx1, conf, out_valid, out_conf, out_pt0);

    // ---- fine refinement ----
    fine_proj_kernel<<<130, b256, 0, stream>>>(fine0, proj_w, proj_b, f0p);
    fine_proj_kernel<<<130, b256, 0, stream>>>(fine1, proj_w, proj_b, f1p);
    fine_match_kernel<<<LTOK, dim3(64), 0, stream>>>(idx0, f0p, f1p, out_pt1);
}

// Round 6
// 919.031 us; speedup vs baseline: 1.8809x; 1.8809x over previous
//
#include <hip/hip_runtime.h>
#include <math.h>

#define LTOK 2080
#define DIM 128
#define NH 4
#define W0C 52
#define HFI 160
#define WFI 208
#define NPIX (HFI*WFI)   // 33280
#define CFCH 32
#define NSPLIT 5
#define PARTSTRIDE 1056  // 32*32 acc + 32 l

// ---------------- transpose (C,L) -> (L,C), batched over 2 images ----------------
__global__ __launch_bounds__(256) void transpose_b_kernel(const float* __restrict__ in0,
                                                          const float* __restrict__ in1,
                                                          float* __restrict__ out0,
                                                          float* __restrict__ out1)
{
    const float* in = blockIdx.z ? in1 : in0;
    float* out = blockIdx.z ? out1 : out0;
    __shared__ float T[32][33];
    int l0 = blockIdx.x * 32, c0 = blockIdx.y * 32;
    int t = threadIdx.x;
    #pragma unroll
    for (int e = 0; e < 4; ++e) {
        int idx = t + e * 256; int i = idx >> 5, j = idx & 31;
        T[i][j] = in[(size_t)(c0 + i) * LTOK + l0 + j];
    }
    __syncthreads();
    #pragma unroll
    for (int e = 0; e < 4; ++e) {
        int idx = t + e * 256; int j2 = idx >> 5, i2 = idx & 31;
        out[(size_t)(l0 + j2) * DIM + c0 + i2] = T[i2][j2];
    }
}

// ---------------- batched GEMM: Cz = Az(MxK) * B(NxK)^T + bias, z = image ----------------
__global__ __launch_bounds__(256) void gemm_nt_b2_kernel(const float* __restrict__ A0,
                                                         const float* __restrict__ A1, int lda,
                                                         const float* __restrict__ B, int ldb,
                                                         float* __restrict__ C0,
                                                         float* __restrict__ C1, int ldc,
                                                         int K,
                                                         const float* __restrict__ bias, int relu)
{
    const float* A = blockIdx.z ? A1 : A0;
    float* C = blockIdx.z ? C1 : C0;
    __shared__ float As[32][33];
    __shared__ float Bs[32][33];
    int tid = threadIdx.x;
    int n0 = blockIdx.x * 32, m0 = blockIdx.y * 32;
    int c = tid & 31, r8 = tid >> 5;
    float acc[4] = {0.f, 0.f, 0.f, 0.f};
    for (int k0 = 0; k0 < K; k0 += 32) {
        #pragma unroll
        for (int e = 0; e < 4; ++e) {
            int l = tid + e * 256;
            int i = l >> 5, k = l & 31;
            As[k][i] = A[(size_t)(m0 + i) * lda + k0 + k];
            Bs[k][i] = B[(size_t)(n0 + i) * ldb + k0 + k];
        }
        __syncthreads();
        #pragma unroll
        for (int k = 0; k < 32; ++k) {
            float bv = Bs[k][c];
            #pragma unroll
            for (int jj = 0; jj < 4; ++jj)
                acc[jj] += As[k][4 * r8 + jj] * bv;
        }
        __syncthreads();
    }
    #pragma unroll
    for (int jj = 0; jj < 4; ++jj) {
        float v = acc[jj];
        if (bias) v += bias[n0 + c];
        if (relu) v = fmaxf(v, 0.f);
        C[(size_t)(m0 + 4 * r8 + jj) * ldc + n0 + c] = v;
    }
}

// ---------------- score GEMM + fused softmax-stat partials ----------------
__global__ __launch_bounds__(256) void gemm_score_kernel(const float* __restrict__ A,
                                                         const float* __restrict__ B,
                                                         float* __restrict__ C,
                                                         float2* __restrict__ prs,
                                                         float2* __restrict__ pcs)
{
    __shared__ float As[32][33];
    __shared__ float Bs[32][33];
    __shared__ float cmS[8][32];
    __shared__ float ceS[8][32];
    int tid = threadIdx.x;
    int n0 = blockIdx.x * 32, m0 = blockIdx.y * 32;
    int c = tid & 31, r8 = tid >> 5;
    float acc[4] = {0.f, 0.f, 0.f, 0.f};
    for (int k0 = 0; k0 < 128; k0 += 32) {
        #pragma unroll
        for (int e = 0; e < 4; ++e) {
            int l = tid + e * 256;
            int i = l >> 5, k = l & 31;
            As[k][i] = A[(size_t)(m0 + i) * 128 + k0 + k];
            Bs[k][i] = B[(size_t)(n0 + i) * 128 + k0 + k];
        }
        __syncthreads();
        #pragma unroll
        for (int k = 0; k < 32; ++k) {
            float bv = Bs[k][c];
            #pragma unroll
            for (int jj = 0; jj < 4; ++jj)
                acc[jj] += As[k][4 * r8 + jj] * bv;
        }
        __syncthreads();
    }
    float v[4];
    #pragma unroll
    for (int jj = 0; jj < 4; ++jj) {
        v[jj] = 10.f * acc[jj];
        C[(size_t)(m0 + 4 * r8 + jj) * LTOK + n0 + c] = v[jj];
    }
    #pragma unroll
    for (int jj = 0; jj < 4; ++jj) {
        float m = v[jj];
        #pragma unroll
        for (int mm = 16; mm >= 1; mm >>= 1) m = fmaxf(m, __shfl_xor(m, mm, 32));
        float e = __expf(v[jj] - m);
        #pragma unroll
        for (int mm = 16; mm >= 1; mm >>= 1) e += __shfl_xor(e, mm, 32);
        if (c == 0) prs[(size_t)blockIdx.x * LTOK + m0 + 4 * r8 + jj] = make_float2(m, e);
    }
    float cmx = fmaxf(fmaxf(v[0], v[1]), fmaxf(v[2], v[3]));
    float cex = __expf(v[0] - cmx) + __expf(v[1] - cmx) + __expf(v[2] - cmx) + __expf(v[3] - cmx);
    cmS[r8][c] = cmx; ceS[r8][c] = cex;
    __syncthreads();
    if (r8 == 0) {
        float M = cmS[0][c], S = ceS[0][c];
        #pragma unroll
        for (int k = 1; k < 8; ++k) {
            float m2 = cmS[k][c], s2 = ceS[k][c];
            if (m2 > M) { S = S * __expf(M - m2) + s2; M = m2; }
            else        { S += s2 * __expf(m2 - M); }
        }
        pcs[(size_t)blockIdx.y * LTOK + n0 + c] = make_float2(M, S);
    }
}

// ---------------- merge 65 stat partials per row/col; store max + 1/sum ----------------
__global__ __launch_bounds__(256) void stats_combine_kernel(const float2* __restrict__ prs,
                                                            const float2* __restrict__ pcs,
                                                            float* __restrict__ rowmax,
                                                            float* __restrict__ rsinv,
                                                            float* __restrict__ colmax,
                                                            float* __restrict__ csinv)
{
    int id = blockIdx.x * 256 + threadIdx.x;
    if (id >= 2 * LTOK) return;
    const float2* p = (id < LTOK) ? (prs + id) : (pcs + (id - LTOK));
    float M = -1e30f;
    for (int i = 0; i < 65; ++i) M = fmaxf(M, p[(size_t)i * LTOK].x);
    float S = 0.f;
    for (int i = 0; i < 65; ++i) {
        float2 f = p[(size_t)i * LTOK];
        S += f.y * __expf(f.x - M);
    }
    if (id < LTOK) { rowmax[id] = M; rsinv[id] = 1.f / S; }
    else           { colmax[id - LTOK] = M; csinv[id - LTOK] = 1.f / S; }
}

// ---------------- P = exp(2S-rm-cm)*rsinv*csinv (in place) + argmax partials ----------------
__global__ __launch_bounds__(256) void dualp_argmax_kernel(float* __restrict__ S,
                                                           const float* __restrict__ rm,
                                                           const float* __restrict__ rsinv,
                                                           const float* __restrict__ cm,
                                                           const float* __restrict__ csinv,
                                                           float* __restrict__ prv,
                                                           int* __restrict__ pri,
                                                           float* __restrict__ pcv,
                                                           int* __restrict__ pci)
{
    __shared__ float cvS[8][32];
    __shared__ int   ciS[8][32];
    int tid = threadIdx.x;
    int n0 = blockIdx.x * 32, m0 = blockIdx.y * 32;
    int c = tid & 31, r8 = tid >> 5;
    int col = n0 + c;
    float cmv = cm[col], csv = csinv[col];
    float p[4];
    #pragma unroll
    for (int jj = 0; jj < 4; ++jj) {
        int row = m0 + 4 * r8 + jj;
        size_t o = (size_t)row * LTOK + col;
        float s = S[o];
        float pv = __expf(2.f * s - rm[row] - cmv) * (rsinv[row] * csv);
        S[o] = pv;
        p[jj] = pv;
    }
    #pragma unroll
    for (int jj = 0; jj < 4; ++jj) {
        float bv = p[jj]; int bi = col;
        #pragma unroll
        for (int mm = 16; mm >= 1; mm >>= 1) {
            float ov = __shfl_xor(bv, mm, 32);
            int   oi = __shfl_xor(bi, mm, 32);
            if (ov > bv || (ov == bv && oi < bi)) { bv = ov; bi = oi; }
        }
        if (c == 0) {
            prv[(size_t)blockIdx.x * LTOK + m0 + 4 * r8 + jj] = bv;
            pri[(size_t)blockIdx.x * LTOK + m0 + 4 * r8 + jj] = bi;
        }
    }
    float bv = p[0]; int bi = m0 + 4 * r8;
    #pragma unroll
    for (int jj = 1; jj < 4; ++jj)
        if (p[jj] > bv) { bv = p[jj]; bi = m0 + 4 * r8 + jj; }
    cvS[r8][c] = bv; ciS[r8][c] = bi;
    __syncthreads();
    if (r8 == 0) {
        #pragma unroll
        for (int k = 1; k < 8; ++k)
            if (cvS[k][c] > bv) { bv = cvS[k][c]; bi = ciS[k][c]; }
        pcv[(size_t)blockIdx.y * LTOK + col] = bv;
        pci[(size_t)blockIdx.y * LTOK + col] = bi;
    }
}

// ---------------- merge 65 argmax partials ----------------
__global__ __launch_bounds__(256) void argmax_combine_kernel(const float* __restrict__ prv,
                                                             const int* __restrict__ pri,
                                                             const float* __restrict__ pcv,
                                                             const int* __restrict__ pci,
                                                             int* __restrict__ idx0,
                                                             float* __restrict__ conf,
                                                             int* __restrict__ idx1)
{
    int id = blockIdx.x * 256 + threadIdx.x;
    if (id >= 2 * LTOK) return;
    if (id < LTOK) {
        float best = -1e30f; int bi = 0;
        for (int i = 0; i < 65; ++i) {
            float v = prv[(size_t)i * LTOK + id];
            if (v > best) { best = v; bi = pri[(size_t)i * LTOK + id]; }
        }
        idx0[id] = bi; conf[id] = best;
    } else {
        int colI = id - LTOK;
        float best = -1e30f; int bi = 0;
        for (int i = 0; i < 65; ++i) {
            float v = pcv[(size_t)i * LTOK + colI];
            if (v > best) { best = v; bi = pci[(size_t)i * LTOK + colI]; }
        }
        idx1[colI] = bi;
    }
}

// ---------------- MHA partial (flash, KV-split, LDS-Ps PV — proven r3 body),
//                  batched over 2 images: blockIdx.y encodes (img,h) ----------------
__global__ __launch_bounds__(256, 4) void mha_partial_b_kernel(const float* __restrict__ qkvA,
                                                               const float* __restrict__ qkvB,
                                                               int cross,
                                                               float* __restrict__ part)
{
    __shared__ float Qs[32][36];
    __shared__ float Ks[64][36];
    __shared__ float Vt[32][68];
    __shared__ float Ps[32][68];
    int tid = threadIdx.x;
    int qb = blockIdx.x, ns = blockIdx.z;
    int img = blockIdx.y >> 2, h = blockIdx.y & 3;
    const float* qsrc  = img ? qkvB : qkvA;
    const float* kvsrc = cross ? (img ? qkvA : qkvB) : qsrc;
    int c = tid & 31, r8 = tid >> 5;
    int row0 = 4 * r8;
    const float sc = 0.17677669529663687f; // 1/sqrt(32)

    {
        int r = tid >> 3, d4 = (tid & 7) << 2;
        float4 q = *(const float4*)(qsrc + (size_t)(qb * 32 + r) * 384 + h * 32 + d4);
        *(float4*)(&Qs[r][d4]) = q;
    }
    float acc[4] = {0.f, 0.f, 0.f, 0.f};
    float lacc[4] = {0.f, 0.f, 0.f, 0.f};
    __syncthreads();

    const int koff = 128 + h * 32, voff = 256 + h * 32;
    for (int t = ns; t < 33; t += NSPLIT) {
        int j0 = t * 64;
        // ---- stage K (64x32) and V transposed (32x64) ----
        {
            int r = tid >> 3, d4 = (tid & 7) << 2;
            int j1 = j0 + r, j2 = j0 + r + 32;
            float4 k1 = *(const float4*)(kvsrc + (size_t)j1 * 384 + koff + d4);
            float4 v1 = *(const float4*)(kvsrc + (size_t)j1 * 384 + voff + d4);
            float4 k2 = make_float4(0.f, 0.f, 0.f, 0.f);
            float4 v2 = make_float4(0.f, 0.f, 0.f, 0.f);
            if (j2 < LTOK) {
                k2 = *(const float4*)(kvsrc + (size_t)j2 * 384 + koff + d4);
                v2 = *(const float4*)(kvsrc + (size_t)j2 * 384 + voff + d4);
            }
            *(float4*)(&Ks[r][d4])      = k1;
            *(float4*)(&Ks[r + 32][d4]) = k2;
            Vt[d4 + 0][r] = v1.x; Vt[d4 + 1][r] = v1.y; Vt[d4 + 2][r] = v1.z; Vt[d4 + 3][r] = v1.w;
            Vt[d4 + 0][r + 32] = v2.x; Vt[d4 + 1][r + 32] = v2.y; Vt[d4 + 2][r + 32] = v2.z; Vt[d4 + 3][r + 32] = v2.w;
        }
        __syncthreads();
        // ---- scores for cols c and c+32 across 4 rows ----
        float s1[4] = {0.f, 0.f, 0.f, 0.f};
        float s2[4] = {0.f, 0.f, 0.f, 0.f};
        #pragma unroll
        for (int d4 = 0; d4 < 8; ++d4) {
            float4 ka = *(const float4*)(&Ks[c][d4 << 2]);
            float4 kb = *(const float4*)(&Ks[c + 32][d4 << 2]);
            #pragma unroll
            for (int jj = 0; jj < 4; ++jj) {
                float4 q = *(const float4*)(&Qs[row0 + jj][d4 << 2]);
                s1[jj] += q.x * ka.x + q.y * ka.y + q.z * ka.z + q.w * ka.w;
                s2[jj] += q.x * kb.x + q.y * kb.y + q.z * kb.z + q.w * kb.w;
            }
        }
        bool ok2 = (j0 + 32 + c) < LTOK;
        #pragma unroll
        for (int jj = 0; jj < 4; ++jj) {
            float p1 = __expf(s1[jj] * sc);
            float p2 = ok2 ? __expf(s2[jj] * sc) : 0.f;
            Ps[row0 + jj][c] = p1;
            Ps[row0 + jj][c + 32] = p2;
            lacc[jj] += p1 + p2;
        }
        __syncthreads();
        // ---- PV: acc[row] += sum_j Ps[row][j] * Vt[c][j] ----
        #pragma unroll
        for (int j4 = 0; j4 < 16; ++j4) {
            float4 vv = *(const float4*)(&Vt[c][j4 << 2]);
            #pragma unroll
            for (int jj = 0; jj < 4; ++jj) {
                float4 pp = *(const float4*)(&Ps[row0 + jj][j4 << 2]);
                acc[jj] += pp.x * vv.x + pp.y * vv.y + pp.z * vv.z + pp.w * vv.w;
            }
        }
        __syncthreads();
    }
    float* pb = part + (size_t)((((size_t)img * 65 + qb) * NH + h) * NSPLIT + ns) * PARTSTRIDE;
    #pragma unroll
    for (int jj = 0; jj < 4; ++jj)
        pb[(row0 + jj) * 32 + c] = acc[jj];
    #pragma unroll
    for (int jj = 0; jj < 4; ++jj) {
        float l = lacc[jj];
        #pragma unroll
        for (int mm = 16; mm >= 1; mm >>= 1) l += __shfl_xor(l, mm, 32);
        if (c == 0) pb[1024 + row0 + jj] = l;
    }
}

// ---------------- MHA combine, batched over 2 images ----------------
__global__ __launch_bounds__(256) void mha_combine_b_kernel(const float* __restrict__ part,
                                                            float* __restrict__ out0,
                                                            float* __restrict__ out1)
{
    int tid = threadIdx.x;
    int qb = blockIdx.x;
    int img = blockIdx.y >> 2, h = blockIdx.y & 3;
    float* out = img ? out1 : out0;
    int c = tid & 31, r8 = tid >> 5;
    int row0 = 4 * r8;
    const float* pb = part + (size_t)(((size_t)img * 65 + qb) * NH + h) * NSPLIT * PARTSTRIDE;
    #pragma unroll
    for (int jj = 0; jj < 4; ++jj) {
        int row = row0 + jj;
        float num = 0.f, den = 0.f;
        #pragma unroll
        for (int ns = 0; ns < NSPLIT; ++ns) {
            num += pb[ns * PARTSTRIDE + row * 32 + c];
            den += pb[ns * PARTSTRIDE + 1024 + row];
        }
        out[(size_t)(qb * 32 + row) * DIM + h * 32 + c] = num / den;
    }
}

// ---------------- residual add + LayerNorm (in place), batched ----------------
__global__ __launch_bounds__(256) void addln_b_kernel(float* __restrict__ f0,
                                                      float* __restrict__ f1,
                                                      const float* __restrict__ t0,
                                                      const float* __restrict__ t1,
                                                      const float* __restrict__ g,
                                                      const float* __restrict__ b)
{
    float* f = blockIdx.y ? f1 : f0;
    const float* t = blockIdx.y ? t1 : t0;
    int row = blockIdx.x * 4 + (threadIdx.x >> 6);
    int lane = threadIdx.x & 63;
    size_t base = (size_t)row * DIM;
    float x0 = f[base + lane] + t[base + lane];
    float x1 = f[base + lane + 64] + t[base + lane + 64];
    float s = x0 + x1;
    #pragma unroll
    for (int mm = 32; mm >= 1; mm >>= 1) s += __shfl_xor(s, mm, 64);
    float mean = s * (1.f / 128.f);
    float d0 = x0 - mean, d1 = x1 - mean;
    float v = d0 * d0 + d1 * d1;
    #pragma unroll
    for (int mm = 32; mm >= 1; mm >>= 1) v += __shfl_xor(v, mm, 64);
    float rstd = rsqrtf(v * (1.f / 128.f) + 1e-5f);
    f[base + lane]      = d0 * rstd * g[lane] + b[lane];
    f[base + lane + 64] = d1 * rstd * g[lane + 64] + b[lane + 64];
}

// ---------------- L2-normalize rows, batched ----------------
__global__ __launch_bounds__(256) void normrows_b_kernel(const float* __restrict__ i0,
                                                         const float* __restrict__ i1,
                                                         float* __restrict__ o0,
                                                         float* __restrict__ o1)
{
    const float* f = blockIdx.y ? i1 : i0;
    float* o = blockIdx.y ? o1 : o0;
    int row = blockIdx.x * 4 + (threadIdx.x >> 6);
    int lane = threadIdx.x & 63;
    size_t base = (size_t)row * DIM;
    float x0 = f[base + lane], x1 = f[base + lane + 64];
    float v = x0 * x0 + x1 * x1;
    #pragma unroll
    for (int mm = 32; mm >= 1; mm >>= 1) v += __shfl_xor(v, mm, 64);
    float inv = 1.f / fmaxf(sqrtf(v), 1e-12f);
    o[base + lane] = x0 * inv;
    o[base + lane + 64] = x1 * inv;
}

// ---------------- match outputs: valid, conf, pt0 ----------------
__global__ __launch_bounds__(256) void match_kernel(const int* __restrict__ idx0,
                                                    const int* __restrict__ idx1,
                                                    const float* __restrict__ conf,
                                                    float* __restrict__ out_valid,
                                                    float* __restrict__ out_conf,
                                                    float* __restrict__ out_pt0)
{
    int i = blockIdx.x * 256 + threadIdx.x;
    if (i >= LTOK) return;
    int j = idx0[i];
    bool valid = (idx1[j] == i) && (conf[i] > 0.2f);
    out_valid[i] = valid ? 1.f : 0.f;
    out_conf[i] = conf[i];
    out_pt0[2 * i]     = (float)(i % W0C) * 8.f + 4.f;
    out_pt0[2 * i + 1] = (float)(i / W0C) * 8.f + 4.f;
}

// ---------------- fine projection, batched ----------------
__global__ __launch_bounds__(256) void fine_proj_b_kernel(const float* __restrict__ fin0,
                                                          const float* __restrict__ fin1,
                                                          const float* __restrict__ w,
                                                          const float* __restrict__ b,
                                                          float* __restrict__ fout0,
                                                          float* __restrict__ fout1)
{
    const float* fin = blockIdx.y ? fin1 : fin0;
    float* fout = blockIdx.y ? fout1 : fout0;
    __shared__ float ws_[32][32];
    __shared__ float bs[32];
    int t = threadIdx.x;
    #pragma unroll
    for (int e = 0; e < 4; ++e) { int l = t + e * 256; ws_[l >> 5][l & 31] = w[l]; }
    if (t < 32) bs[t] = b[t];
    __syncthreads();
    int p = blockIdx.x * 256 + t;
    if (p >= NPIX) return;
    float x[32];
    #pragma unroll
    for (int cc = 0; cc < 32; ++cc) x[cc] = fin[(size_t)cc * NPIX + p];
    #pragma unroll
    for (int o = 0; o < 32; ++o) {
        float a = bs[o];
        #pragma unroll
        for (int cc = 0; cc < 32; ++cc) a += ws_[o][cc] * x[cc];
        fout[(size_t)o * NPIX + p] = a;
    }
}

// ---------------- fine match ----------------
__global__ __launch_bounds__(64) void fine_match_kernel(const int* __restrict__ idx0,
                                                        const float* __restrict__ f0p,
                                                        const float* __restrict__ f1p,
                                                        float* __restrict__ out_pt1)
{
    int i = blockIdx.x;
    int l = threadIdx.x;
    int j = idx0[i];
    int m0x = i % W0C, m0y = i / W0C;
    int m1x = j % W0C, m1y = j / W0C;
    int c0x = m0x * 4, c0y = m0y * 4, c1x = m1x * 4, c1y = m1y * 4;
    bool inb = (c0x - 2 >= 0) && (c0x + 2 < WFI) && (c0y - 2 >= 0) && (c0y + 2 < HFI)
            && (c1x - 2 >= 0) && (c1x + 2 < WFI) && (c1y - 2 >= 0) && (c1y + 2 < HFI);
    int cy0 = min(max(c0y, 2), HFI - 3), cx0 = min(max(c0x, 2), WFI - 3);
    int cy1 = min(max(c1y, 2), HFI - 3), cx1 = min(max(c1x, 2), WFI - 3);
    int dy = l / 5 - 2, dx = l % 5 - 2;
    float corr = -1e30f;
    if (l < 25) {
        float a = 0.f;
        int p0 = cy0 * WFI + cx0;
        int p1 = (cy1 + dy) * WFI + (cx1 + dx);
        #pragma unroll
        for (int cc = 0; cc < 32; ++cc)
            a += f0p[(size_t)cc * NPIX + p0] * f1p[(size_t)cc * NPIX + p1];
        corr = a;
    }
    float mx = corr;
    #pragma unroll
    for (int mm = 32; mm >= 1; mm >>= 1) mx = fmaxf(mx, __shfl_xor(mx, mm, 64));
    float p = (l < 25) ? expf(corr - mx) : 0.f;
    float s = p, sx = p * (float)dx, sy = p * (float)dy;
    #pragma unroll
    for (int mm = 32; mm >= 1; mm >>= 1) {
        s  += __shfl_xor(s, mm, 64);
        sx += __shfl_xor(sx, mm, 64);
        sy += __shfl_xor(sy, mm, 64);
    }
    if (l == 0) {
        float offx = sx / s, offy = sy / s;
        float px = (float)m1x * 8.f + 4.f;
        float py = (float)m1y * 8.f + 4.f;
        if (inb) { px += offx * 2.f; py += offy * 2.f; }
        out_pt1[2 * i]     = px;
        out_pt1[2 * i + 1] = py;
    }
}

// ---------------- host launch ----------------
extern "C" void kernel_launch(void* const* d_in, const int* in_sizes, int n_in,
                              void* d_out, int out_size, void* d_ws, size_t ws_size,
                              hipStream_t stream) {
    (void)in_sizes; (void)n_in; (void)out_size; (void)ws_size;
    const float* coarse0 = (const float*)d_in[0];
    const float* coarse1 = (const float*)d_in[1];
    const float* fine0   = (const float*)d_in[2];
    const float* fine1   = (const float*)d_in[3];
    const float* sa_in_w  = (const float*)d_in[4];
    const float* sa_in_b  = (const float*)d_in[5];
    const float* sa_out_w = (const float*)d_in[6];
    const float* sa_out_b = (const float*)d_in[7];
    const float* ca_in_w  = (const float*)d_in[8];
    const float* ca_in_b  = (const float*)d_in[9];
    const float* ca_out_w = (const float*)d_in[10];
    const float* ca_out_b = (const float*)d_in[11];
    const float* sn_g = (const float*)d_in[12];
    const float* sn_b = (const float*)d_in[13];
    const float* cn_g = (const float*)d_in[14];
    const float* cn_b = (const float*)d_in[15];
    const float* ffn_w1 = (const float*)d_in[16];
    const float* ffn_b1 = (const float*)d_in[17];
    const float* ffn_w2 = (const float*)d_in[18];
    const float* ffn_b2 = (const float*)d_in[19];
    const float* fn_g = (const float*)d_in[20];
    const float* fn_b = (const float*)d_in[21];
    const float* proj_w = (const float*)d_in[22];
    const float* proj_b = (const float*)d_in[23];

    float* w = (float*)d_ws;
    float* f0   = w; w += (size_t)LTOK * DIM;
    float* f1   = w; w += (size_t)LTOK * DIM;
    float* qkv0 = w; w += (size_t)LTOK * 384;
    float* qkv1 = w; w += (size_t)LTOK * 384;
    float* att0 = w; w += (size_t)LTOK * DIM;
    float* att1 = w; w += (size_t)LTOK * DIM;
    float* tmp0 = w; w += (size_t)LTOK * DIM;
    float* tmp1 = w; w += (size_t)LTOK * DIM;
    float* f0n  = w; w += (size_t)LTOK * DIM;
    float* f1n  = w; w += (size_t)LTOK * DIM;
    // R1: time-shared region — part (MHA phase) | hid0/hid1 (FFN phase) | f0p/f1p (fine phase)
    float* R1   = w; w += (size_t)2 * 65 * NH * NSPLIT * PARTSTRIDE;  // 2,745,600 floats (largest)
    float* rowmax = w; w += LTOK;
    float* rsinv  = w; w += LTOK;
    float* colmax = w; w += LTOK;
    float* csinv  = w; w += LTOK;
    float* conf   = w; w += LTOK;
    int* idx0 = (int*)w; w += LTOK;
    int* idx1 = (int*)w; w += LTOK;

    float* part = R1;
    float* hid0 = R1;
    float* hid1 = R1 + (size_t)LTOK * 256;
    float* f0p  = R1;
    float* f1p  = R1 + (size_t)CFCH * NPIX;

    // matching-tail partials alias the (dead after transformer loop) qkv buffers
    float2* prs = (float2*)qkv0;
    float2* pcs = (float2*)(qkv0 + 2 * 65 * LTOK);
    float*  prv = qkv1;
    int*    pri = (int*)(qkv1 + 65 * LTOK);
    float*  pcv = qkv1 + 2 * 65 * LTOK;
    int*    pci = (int*)(qkv1 + 3 * 65 * LTOK);

    float* Pout = (float*)d_out;
    float* out_valid = Pout + (size_t)LTOK * LTOK;
    float* out_conf  = out_valid + LTOK;
    float* out_pt0   = out_conf + LTOK;
    float* out_pt1   = out_pt0 + 2 * LTOK;

    dim3 b256(256);
    dim3 gMHA(65, 8, NSPLIT);
    dim3 gCMB(65, 8);
    dim3 gLN(520, 2);
    transpose_b_kernel<<<dim3(65, 4, 2), b256, 0, stream>>>(coarse0, coarse1, f0, f1);

    for (int i = 0; i < 2; ++i) {
        const float* saw = sa_in_w + (size_t)i * 384 * 128;
        const float* sab = sa_in_b + (size_t)i * 384;
        const float* sow = sa_out_w + (size_t)i * 128 * 128;
        const float* sob = sa_out_b + (size_t)i * 128;
        const float* caw = ca_in_w + (size_t)i * 384 * 128;
        const float* cab = ca_in_b + (size_t)i * 384;
        const float* cow = ca_out_w + (size_t)i * 128 * 128;
        const float* cob = ca_out_b + (size_t)i * 128;
        const float* w1 = ffn_w1 + (size_t)i * 256 * 128;
        const float* b1 = ffn_b1 + (size_t)i * 256;
        const float* w2 = ffn_w2 + (size_t)i * 128 * 256;
        const float* b2 = ffn_b2 + (size_t)i * 128;

        // ---- self attention ----
        gemm_nt_b2_kernel<<<dim3(12, 65, 2), b256, 0, stream>>>(f0, f1, 128, saw, 128, qkv0, qkv1, 384, 128, sab, 0);
        mha_partial_b_kernel<<<gMHA, b256, 0, stream>>>(qkv0, qkv1, 0, part);
        mha_combine_b_kernel<<<gCMB, b256, 0, stream>>>(part, att0, att1);
        gemm_nt_b2_kernel<<<dim3(4, 65, 2), b256, 0, stream>>>(att0, att1, 128, sow, 128, tmp0, tmp1, 128, 128, sob, 0);
        addln_b_kernel<<<gLN, b256, 0, stream>>>(f0, f1, tmp0, tmp1, sn_g + (size_t)i * 128, sn_b + (size_t)i * 128);

        // ---- cross attention ----
        gemm_nt_b2_kernel<<<dim3(12, 65, 2), b256, 0, stream>>>(f0, f1, 128, caw, 128, qkv0, qkv1, 384, 128, cab, 0);
        mha_partial_b_kernel<<<gMHA, b256, 0, stream>>>(qkv0, qkv1, 1, part);
        mha_combine_b_kernel<<<gCMB, b256, 0, stream>>>(part, att0, att1);
        gemm_nt_b2_kernel<<<dim3(4, 65, 2), b256, 0, stream>>>(att0, att1, 128, cow, 128, tmp0, tmp1, 128, 128, cob, 0);
        addln_b_kernel<<<gLN, b256, 0, stream>>>(f0, f1, tmp0, tmp1, cn_g + (size_t)i * 128, cn_b + (size_t)i * 128);

        // ---- FFN ----
        gemm_nt_b2_kernel<<<dim3(8, 65, 2), b256, 0, stream>>>(f0, f1, 128, w1, 128, hid0, hid1, 256, 128, b1, 1);
        gemm_nt_b2_kernel<<<dim3(4, 65, 2), b256, 0, stream>>>(hid0, hid1, 256, w2, 256, tmp0, tmp1, 128, 256, b2, 0);
        addln_b_kernel<<<gLN, b256, 0, stream>>>(f0, f1, tmp0, tmp1, fn_g + (size_t)i * 128, fn_b + (size_t)i * 128);
    }

    // ---- matching (2 matrix passes total) ----
    normrows_b_kernel<<<gLN, b256, 0, stream>>>(f0, f1, f0n, f1n);
    gemm_score_kernel<<<dim3(65, 65), b256, 0, stream>>>(f0n, f1n, Pout, prs, pcs);
    stats_combine_kernel<<<17, b256, 0, stream>>>(prs, pcs, rowmax, rsinv, colmax, csinv);
    dualp_argmax_kernel<<<dim3(65, 65), b256, 0, stream>>>(Pout, rowmax, rsinv, colmax, csinv,
                                                           prv, pri, pcv, pci);
    argmax_combine_kernel<<<17, b256, 0, stream>>>(prv, pri, pcv, pci, idx0, conf, idx1);
    match_kernel<<<9, b256, 0, stream>>>(idx0, idx1, conf, out_valid, out_conf, out_pt0);

    // ---- fine refinement ----
    fine_proj_b_kernel<<<dim3(130, 2), b256, 0, stream>>>(fine0, fine1, proj_w, proj_b, f0p, f1p);
    fine_match_kernel<<<LTOK, dim3(64), 0, stream>>>(idx0, f0p, f1p, out_pt1);
}